// Round 2
// baseline (30656.238 us; speedup 1.0000x reference)
//
#include <hip/hip_runtime.h>

typedef _Float16 f16;
typedef _Float16 f16x8 __attribute__((ext_vector_type(8)));
typedef float f32x4 __attribute__((ext_vector_type(4)));

static constexpr int kS = 1024;   // timesteps

// workspace layout (bytes); total ~44.1 MB
static constexpr size_t OFF_WP = 0;                        // f16 [8192][2048] packed gate weights (h part)
static constexpr size_t OFF_WX = 33554432;                 // f32 [8192] column 0 (x weight)
static constexpr size_t OFF_BB = OFF_WX + 32768;           // f32 [8192] bias
static constexpr size_t OFF_XT = OFF_BB + 32768;           // f32 [1024][512] x transposed
static constexpr size_t OFF_HA = OFF_XT + 2097152;         // f16 [512][2048] h ping
static constexpr size_t OFF_HB = OFF_HA + 2097152;         // f16 [512][2048] h pong
static constexpr size_t OFF_CB = OFF_HB + 2097152;         // f32 [256 blk][256 thr][16] cell state

__device__ __forceinline__ void gload16(const void* g, void* l) {
  __builtin_amdgcn_global_load_lds(
      (const __attribute__((address_space(1))) unsigned int*)g,
      (__attribute__((address_space(3))) unsigned int*)l, 16, 0, 0);
}

__device__ __forceinline__ float sigf(float x) { return 1.f / (1.f + __expf(-x)); }
__device__ __forceinline__ float tanh_fast(float x) {
  float e = __expf(2.f * x);
  return 1.f - 2.f / (e + 1.f);   // +-inf safe: -> 1 / -1
}

// Pack W rows into order (unit*4 + gate), fp16, h-columns only (cols 1..2048).
// Row R -> unit u = (R>>8)*64 + ((R&255)>>2), gate = R&3.
__global__ void pack_weights(const float* __restrict__ Wg, const float* __restrict__ Wi,
                             const float* __restrict__ Wf, const float* __restrict__ Wo,
                             const float* __restrict__ bg, const float* __restrict__ bi,
                             const float* __restrict__ bf, const float* __restrict__ bo,
                             f16* __restrict__ Wp, float* __restrict__ wx, float* __restrict__ bb)
{
  const int R = blockIdx.x;
  const int p = R >> 8, r = R & 255;
  const int u = (p << 6) + (r >> 2), gsel = r & 3;
  const float* Wsrc = (gsel == 0) ? Wg : (gsel == 1) ? Wi : (gsel == 2) ? Wf : Wo;
  const float* bsrc = (gsel == 0) ? bg : (gsel == 1) ? bi : (gsel == 2) ? bf : bo;
  const float* src = Wsrc + (size_t)u * 2049;
  const int k = threadIdx.x * 8;
#pragma unroll
  for (int j = 0; j < 8; ++j)
    Wp[(size_t)R * 2048 + k + j] = (f16)src[1 + k + j];
  if (threadIdx.x == 0) { wx[R] = src[0]; bb[R] = bsrc[u]; }
}

__global__ void transpose_x(const float* __restrict__ x, float* __restrict__ xT) {
  const int idx = blockIdx.x * 256 + threadIdx.x;   // 512*1024
  const int b = idx >> 10, t = idx & 1023;
  xT[t * 512 + b] = x[idx];
}

__global__ void zero_h(f16* hA) {
  const int idx = blockIdx.x * 256 + threadIdx.x;   // 131072 x 16B = 2MB
  ((uint4*)hA)[idx] = make_uint4(0u, 0u, 0u, 0u);
}

// One LSTM timestep: 256 blocks x 256 threads, block = 64 units x 64 batch.
// z[256 packed rows][64 batch] = Wp_panel[256][2048] * hin^T; then cell update.
// Wave w owns packed rows [64w,64w+64): the 4 acc regs of a 16x16 frag are one
// unit's (g,i,f,o) -> cell update fully register-local. c persists in cbuf.
__global__ __launch_bounds__(256, 1) void lstm_step(
    const f16* __restrict__ Wp, const float* __restrict__ wx,
    const float* __restrict__ bb, const float* __restrict__ xT,
    const f16* __restrict__ hin, f16* __restrict__ hout,
    float* __restrict__ cbuf, int t)
{
  extern __shared__ __align__(16) char smem[];
  f16* ldsA = (f16*)smem;                 // [2][256][64] f16 (64 KB)
  f16* ldsB = (f16*)(smem + 65536);       // [2][64][64]  f16 (16 KB)
  f16* ldsH = (f16*)smem;                 // [64][72] h-out tile, aliases ldsA buf0 (used only after last chunk barrier)

  const int blk = blockIdx.x;
  // XCD affinity: the 8 batch-panels sharing a weight panel have the same blk%8.
  const int p  = (blk & 7) + 8 * (blk >> 6);           // unit panel 0..31
  const int bp = (blk >> 3) & 7;                        // batch panel 0..7
  const int u0 = p * 64, b0 = bp * 64;

  const int tid = threadIdx.x;
  const int w = tid >> 6, l = tid & 63;
  const int l15 = l & 15, hi = l >> 4;
  const int r3 = l >> 3, c7 = l & 7;
  const int ksw = (c7 ^ r3) * 8;   // staging source swizzle (elements); involution per row mod 8

  // per-thread row constants: x-weight and bias for 4 subtiles x 4 gates
  float wxr[4][4], br[4][4];
#pragma unroll
  for (int ni = 0; ni < 4; ++ni)
#pragma unroll
    for (int r = 0; r < 4; ++r) {
      const int R = p * 256 + w * 64 + ni * 16 + hi * 4 + r;
      wxr[ni][r] = wx[R];
      br[ni][r] = bb[R];
    }

  // x_t for this thread's 4 batch columns
  float xv[4];
#pragma unroll
  for (int bj = 0; bj < 4; ++bj)
    xv[bj] = xT[t * 512 + b0 + bj * 16 + l15];

  // cell state: per-thread contiguous, coalesced float4
  float* cme = cbuf + ((size_t)blk * 256 + tid) * 16;
  float cst[4][4];
  if (t == 0) {
#pragma unroll
    for (int ni = 0; ni < 4; ++ni)
#pragma unroll
      for (int bj = 0; bj < 4; ++bj) cst[ni][bj] = 0.f;
  } else {
#pragma unroll
    for (int ni = 0; ni < 4; ++ni) {
      const float4 cv = *(const float4*)(cme + ni * 4);
      cst[ni][0] = cv.x; cst[ni][1] = cv.y; cst[ni][2] = cv.z; cst[ni][3] = cv.w;
    }
  }

  auto stage = [&](int ch) {
    const int buf = ch & 1;
    const int k0 = ch * 64;
    // A: this wave's 64 weight rows (8 issues x 1KB), linear LDS dest, swizzled source
#pragma unroll
    for (int j = 0; j < 8; ++j) {
      const int row = w * 64 + j * 8 + r3;
      gload16(Wp + (size_t)(p * 256 + row) * 2048 + (k0 + ksw),
              ldsA + buf * 16384 + (w * 64 + j * 8) * 64);
    }
    // B: h tile rows (2 issues per wave)
#pragma unroll
    for (int j = 0; j < 2; ++j) {
      const int rb = w * 16 + j * 8 + r3;
      gload16(hin + (size_t)(b0 + rb) * 2048 + (k0 + ksw),
              ldsB + buf * 4096 + (w * 16 + j * 8) * 64);
    }
  };

  stage(0);
  __syncthreads();

  f32x4 acc[4][4];
#pragma unroll
  for (int ni = 0; ni < 4; ++ni) {
    f32x4 v;
    v[0] = br[ni][0]; v[1] = br[ni][1]; v[2] = br[ni][2]; v[3] = br[ni][3];
#pragma unroll
    for (int bj = 0; bj < 4; ++bj) acc[ni][bj] = v;   // bias pre-folded
  }

#pragma unroll 2
  for (int ch = 0; ch < 32; ++ch) {
    if (ch < 31) stage(ch + 1);
    const f16* A  = ldsA + (ch & 1) * 16384;
    const f16* Bm = ldsB + (ch & 1) * 4096;
#pragma unroll
    for (int ks = 0; ks < 2; ++ks) {
      const int sw = ((ks * 4 + hi) ^ c7) * 8;   // un-swizzle on read
      f16x8 af[4], bf4[4];
#pragma unroll
      for (int ni = 0; ni < 4; ++ni)
        af[ni] = *(const f16x8*)(A + (w * 64 + ni * 16 + l15) * 64 + sw);
#pragma unroll
      for (int bj = 0; bj < 4; ++bj)
        bf4[bj] = *(const f16x8*)(Bm + (bj * 16 + l15) * 64 + sw);
#pragma unroll
      for (int ni = 0; ni < 4; ++ni)
#pragma unroll
        for (int bj = 0; bj < 4; ++bj)
          acc[ni][bj] = __builtin_amdgcn_mfma_f32_16x16x32_f16(af[ni], bf4[bj], acc[ni][bj], 0, 0, 0);
    }
    __syncthreads();
  }

  // epilogue: cell update, fully register-local (acc regs = one unit's g,i,f,o)
#pragma unroll
  for (int ni = 0; ni < 4; ++ni) {
    float cnew[4];
#pragma unroll
    for (int bj = 0; bj < 4; ++bj) {
      const f32x4 a = acc[ni][bj];
      const float z0 = a[0] + xv[bj] * wxr[ni][0];
      const float z1 = a[1] + xv[bj] * wxr[ni][1];
      const float z2 = a[2] + xv[bj] * wxr[ni][2];
      const float z3 = a[3] + xv[bj] * wxr[ni][3];
      const float gg = tanh_fast(z0);
      const float ig = sigf(z1);
      const float fg = sigf(z2);
      const float og = sigf(z3);
      const float cc = gg * ig + cst[ni][bj] * fg;
      cnew[bj] = cc;
      const float hh = tanh_fast(cc) * og;
      ldsH[(bj * 16 + l15) * 72 + (w * 16 + ni * 4 + hi)] = (f16)hh;  // [b][u], pad 72
    }
    *(float4*)(cme + ni * 4) = make_float4(cnew[0], cnew[1], cnew[2], cnew[3]);
  }
  __syncthreads();

  // coalesced h-tile writeout (2 x 16B per thread)
#pragma unroll
  for (int j = 0; j < 2; ++j) {
    const int q = tid + j * 256;
    const int row = q >> 3, uc = q & 7;
    const f16x8 v = *(const f16x8*)(ldsH + row * 72 + uc * 8);
    *(f16x8*)(hout + (size_t)(b0 + row) * 2048 + u0 + uc * 8) = v;
  }
}

// y[b][o] = sum_k h[b][k]*Wy[o][k] + by[o]  (one-shot, fp32)
__global__ void out_proj(const f16* __restrict__ h, const float* __restrict__ Wy,
                         const float* __restrict__ by, float* __restrict__ y)
{
  const int gi = blockIdx.x * 256 + threadIdx.x;   // 65536
  const int o = gi & 127, b = gi >> 7;
  const f16* hr = h + (size_t)b * 2048;
  const float* wr = Wy + (size_t)o * 2048;
  float acc = 0.f;
  for (int k = 0; k < 2048; k += 8) {
    const f16x8 hv = *(const f16x8*)(hr + k);
    const float4 wa = *(const float4*)(wr + k);
    const float4 wb = *(const float4*)(wr + k + 4);
    acc += (float)hv[0] * wa.x + (float)hv[1] * wa.y + (float)hv[2] * wa.z + (float)hv[3] * wa.w
         + (float)hv[4] * wb.x + (float)hv[5] * wb.y + (float)hv[6] * wb.z + (float)hv[7] * wb.w;
  }
  y[gi] = acc + by[o];
}

extern "C" void kernel_launch(void* const* d_in, const int* in_sizes, int n_in,
                              void* d_out, int out_size, void* d_ws, size_t ws_size,
                              hipStream_t stream)
{
  const float* x  = (const float*)d_in[0];
  const float* Wg = (const float*)d_in[1];
  const float* bg = (const float*)d_in[2];
  const float* Wi = (const float*)d_in[3];
  const float* bi = (const float*)d_in[4];
  const float* Wf = (const float*)d_in[5];
  const float* bf = (const float*)d_in[6];
  const float* Wo = (const float*)d_in[7];
  const float* bo = (const float*)d_in[8];
  const float* Wy = (const float*)d_in[9];
  const float* by = (const float*)d_in[10];
  float* y = (float*)d_out;

  char* ws = (char*)d_ws;
  f16*   Wp = (f16*)(ws + OFF_WP);
  float* wx = (float*)(ws + OFF_WX);
  float* bb = (float*)(ws + OFF_BB);
  float* xT = (float*)(ws + OFF_XT);
  f16*   hA = (f16*)(ws + OFF_HA);
  f16*   hB = (f16*)(ws + OFF_HB);
  float* cb = (float*)(ws + OFF_CB);

  pack_weights<<<8192, 256, 0, stream>>>(Wg, Wi, Wf, Wo, bg, bi, bf, bo, Wp, wx, bb);
  transpose_x<<<2048, 256, 0, stream>>>(x, xT);
  zero_h<<<512, 256, 0, stream>>>(hA);

  (void)hipFuncSetAttribute((const void*)lstm_step,
                            hipFuncAttributeMaxDynamicSharedMemorySize, 131072);
  for (int t = 0; t < kS; ++t) {
    const f16* hin = (t & 1) ? hB : hA;
    f16*      hout = (t & 1) ? hA : hB;
    lstm_step<<<256, 256, 81920, stream>>>(Wp, wx, bb, xT, hin, hout, cb, t);
  }

  out_proj<<<256, 256, 0, stream>>>(hA, Wy, by, y);
}

// Round 4
// 30261.002 us; speedup vs baseline: 1.0131x; 1.0131x over previous
//
#include <hip/hip_runtime.h>

typedef _Float16 f16;
typedef _Float16 f16x8 __attribute__((ext_vector_type(8)));
typedef float f32x4 __attribute__((ext_vector_type(4)));

static constexpr int kS = 1024;   // timesteps

// workspace layout (bytes); total ~42.2 MB
static constexpr size_t OFF_WP = 0;                        // f16 [8192][2048] packed gate weights (h part)
static constexpr size_t OFF_WX = 33554432;                 // f32 [8192] column 0 (x weight)
static constexpr size_t OFF_BB = OFF_WX + 32768;           // f32 [8192] bias
static constexpr size_t OFF_XT = OFF_BB + 32768;           // f32 [1024][512] x transposed
static constexpr size_t OFF_HA = OFF_XT + 2097152;         // f16 [512][2048] h ping
static constexpr size_t OFF_HB = OFF_HA + 2097152;         // f16 [512][2048] h pong
static constexpr size_t OFF_CB = OFF_HB + 2097152;         // f32 [256 blk][256 thr][16] cell state

__device__ __forceinline__ void gload16(const void* g, void* l) {
  __builtin_amdgcn_global_load_lds(
      (const __attribute__((address_space(1))) unsigned int*)g,
      (__attribute__((address_space(3))) unsigned int*)l, 16, 0, 0);
}

__device__ __forceinline__ float sigf(float x) { return 1.f / (1.f + __expf(-x)); }
__device__ __forceinline__ float tanh_fast(float x) {
  float e = __expf(2.f * x);
  return 1.f - 2.f / (e + 1.f);   // +-inf safe: -> 1 / -1
}

// Pack W rows into order (unit*4 + gate), fp16, h-columns only (cols 1..2048).
// Row R -> unit u = (R>>8)*64 + ((R&255)>>2), gate = R&3.  (mapping is global,
// independent of the lstm_step tiling)
__global__ void pack_weights(const float* __restrict__ Wg, const float* __restrict__ Wi,
                             const float* __restrict__ Wf, const float* __restrict__ Wo,
                             const float* __restrict__ bg, const float* __restrict__ bi,
                             const float* __restrict__ bf, const float* __restrict__ bo,
                             f16* __restrict__ Wp, float* __restrict__ wx, float* __restrict__ bb)
{
  const int R = blockIdx.x;
  const int p = R >> 8, r = R & 255;
  const int u = (p << 6) + (r >> 2), gsel = r & 3;
  const float* Wsrc = (gsel == 0) ? Wg : (gsel == 1) ? Wi : (gsel == 2) ? Wf : Wo;
  const float* bsrc = (gsel == 0) ? bg : (gsel == 1) ? bi : (gsel == 2) ? bf : bo;
  const float* src = Wsrc + (size_t)u * 2049;
  const int k = threadIdx.x * 8;
#pragma unroll
  for (int j = 0; j < 8; ++j)
    Wp[(size_t)R * 2048 + k + j] = (f16)src[1 + k + j];
  if (threadIdx.x == 0) { wx[R] = src[0]; bb[R] = bsrc[u]; }
}

__global__ void transpose_x(const float* __restrict__ x, float* __restrict__ xT) {
  const int idx = blockIdx.x * 256 + threadIdx.x;   // 512*1024
  const int b = idx >> 10, t = idx & 1023;
  xT[t * 512 + b] = x[idx];
}

__global__ void zero_h(f16* hA) {
  const int idx = blockIdx.x * 256 + threadIdx.x;   // 131072 x 16B = 2MB
  ((uint4*)hA)[idx] = make_uint4(0u, 0u, 0u, 0u);
}

// One LSTM timestep: 256 blocks x 256 threads; block tile = 32 units (128
// packed rows) x 128 batch. C=128 halves weight re-reads vs C=64 (4 batch
// panels per weight panel instead of 8): weight stream 128 MB/step.
// Wave grid 2x2: wave (wr,wc) owns rows [wr*64,+64) x cols [wc*64,+64),
// acc 4x4 frags of 16x16x32 f16 MFMA. Depth-3 LDS staging queue with counted
// vmcnt (never drains to 0 mid-loop) + raw s_barrier.
// Thread's 4 acc regs of a frag = one unit's (g,i,f,o) -> register-local cell
// update. c persists in cbuf (NT), h ping-pongs (NT store).
__global__ __launch_bounds__(256, 1) void lstm_step(
    const f16* __restrict__ Wp, const float* __restrict__ wx,
    const float* __restrict__ bb, const float* __restrict__ xT,
    const f16* __restrict__ hin, f16* __restrict__ hout,
    float* __restrict__ cbuf, int t)
{
  extern __shared__ __align__(16) char smem[];
  f16* ldsA = (f16*)smem;                 // [3][128][64] f16 (48 KB)
  f16* ldsB = (f16*)(smem + 49152);       // [3][128][64] f16 (48 KB)
  f16* ldsH = (f16*)smem;                 // [128][40] h-out tile, aliases ldsA buf0 (used after final barrier)

  const int blk = blockIdx.x;
  // XCD affinity (blk%8 round-robin heuristic): the 4 batch-panels sharing a
  // weight panel land on one XCD; per XCD 8 panels x 0.5 MB = 4 MB footprint.
  const int p  = (blk & 7) + 8 * (blk >> 5);           // weight panel 0..63
  const int bp = (blk >> 3) & 3;                        // batch panel 0..3
  const int u0 = p * 32, b0 = bp * 128;

  const int tid = threadIdx.x;
  const int w = tid >> 6, l = tid & 63;
  const int wr = w >> 1, wc = w & 1;
  const int l15 = l & 15, hi = l >> 4;
  const int r3 = l >> 3, c7 = l & 7;
  const int ksw = (c7 ^ r3) * 8;   // staging source swizzle (elements); involution per row mod 8

  // per-thread row constants: x-weight and bias for 4 subtiles x 4 gates
  float wxr[4][4], br[4][4];
#pragma unroll
  for (int ni = 0; ni < 4; ++ni)
#pragma unroll
    for (int r = 0; r < 4; ++r) {
      const int R = p * 128 + wr * 64 + ni * 16 + hi * 4 + r;
      wxr[ni][r] = wx[R];
      br[ni][r] = bb[R];
    }

  // x_t for this thread's 4 batch columns
  float xv[4];
#pragma unroll
  for (int bj = 0; bj < 4; ++bj)
    xv[bj] = xT[t * 512 + b0 + wc * 64 + bj * 16 + l15];

  // cell state: per-thread contiguous, NT (zero reuse within a step)
  float* cme = cbuf + ((size_t)blk * 256 + tid) * 16;
  float cst[4][4];
  if (t == 0) {
#pragma unroll
    for (int ni = 0; ni < 4; ++ni)
#pragma unroll
      for (int bj = 0; bj < 4; ++bj) cst[ni][bj] = 0.f;
  } else {
#pragma unroll
    for (int ni = 0; ni < 4; ++ni) {
      const f32x4 cv = __builtin_nontemporal_load((const f32x4*)(cme + ni * 4));
      cst[ni][0] = cv[0]; cst[ni][1] = cv[1]; cst[ni][2] = cv[2]; cst[ni][3] = cv[3];
    }
  }

  // stage chunk ch (K columns [ch*64, ch*64+64)) into buffer buf.
  // 8 gload16 per thread-wave instr stream: A 4 + B 4.
  auto stage = [&](int ch, int buf) {
    const size_t kof = (size_t)ch * 64 + ksw;
#pragma unroll
    for (int j = 0; j < 4; ++j) {
      const int row = w * 32 + j * 8;     // +r3 on source; LDS dest linear
      gload16(Wp + (size_t)(p * 128 + row + r3) * 2048 + kof,
              ldsA + buf * 8192 + row * 64);
    }
#pragma unroll
    for (int j = 0; j < 4; ++j) {
      const int row = w * 32 + j * 8;
      gload16(hin + (size_t)(b0 + row + r3) * 2048 + kof,
              ldsB + buf * 8192 + row * 64);
    }
  };

  f32x4 acc[4][4];
#pragma unroll
  for (int ni = 0; ni < 4; ++ni) {
    f32x4 v;
    v[0] = br[ni][0]; v[1] = br[ni][1]; v[2] = br[ni][2]; v[3] = br[ni][3];
#pragma unroll
    for (int bj = 0; bj < 4; ++bj) acc[ni][bj] = v;   // bias pre-folded
  }

  // prologue: fill 2 of 3 buffers
  stage(0, 0);
  stage(1, 1);

  int bufc = 0;   // buffer consumed this iteration = ch % 3
#pragma unroll 1
  for (int ch = 0; ch < 32; ++ch) {
    if (ch < 30) {
      int bufs = bufc - 1; if (bufs < 0) bufs = 2;    // (ch+2) % 3
      stage(ch + 2, bufs);
      // 24 stage-instrs outstanding; wait until oldest chunk's 8 are done.
      asm volatile("s_waitcnt vmcnt(16)" ::: "memory");
    } else if (ch == 30) {
      asm volatile("s_waitcnt vmcnt(8)" ::: "memory");
    } else {
      asm volatile("s_waitcnt vmcnt(0)" ::: "memory");
    }
    __builtin_amdgcn_sched_barrier(0);
    __builtin_amdgcn_s_barrier();        // all waves' chunk-ch data in LDS
    __builtin_amdgcn_sched_barrier(0);

    const f16* A  = ldsA + bufc * 8192;
    const f16* Bm = ldsB + bufc * 8192;
#pragma unroll
    for (int ks = 0; ks < 2; ++ks) {
      const int sw = ((ks * 4 + hi) ^ c7) * 8;   // un-swizzle on read
      f16x8 af[4], bfr[4];
#pragma unroll
      for (int ni = 0; ni < 4; ++ni)
        af[ni] = *(const f16x8*)(A + (wr * 64 + ni * 16 + l15) * 64 + sw);
#pragma unroll
      for (int bj = 0; bj < 4; ++bj)
        bfr[bj] = *(const f16x8*)(Bm + (wc * 64 + bj * 16 + l15) * 64 + sw);
#pragma unroll
      for (int ni = 0; ni < 4; ++ni)
#pragma unroll
        for (int bj = 0; bj < 4; ++bj)
          acc[ni][bj] = __builtin_amdgcn_mfma_f32_16x16x32_f16(af[ni], bfr[bj], acc[ni][bj], 0, 0, 0);
    }

    __builtin_amdgcn_sched_barrier(0);
    __builtin_amdgcn_s_barrier();        // everyone done reading buf ch -> reusable
    bufc = (bufc == 2) ? 0 : bufc + 1;
  }

  // epilogue: cell update, fully register-local (acc regs = one unit's g,i,f,o)
#pragma unroll
  for (int ni = 0; ni < 4; ++ni) {
    f32x4 cnew;
#pragma unroll
    for (int bj = 0; bj < 4; ++bj) {
      const f32x4 a = acc[ni][bj];
      const float z0 = a[0] + xv[bj] * wxr[ni][0];
      const float z1 = a[1] + xv[bj] * wxr[ni][1];
      const float z2 = a[2] + xv[bj] * wxr[ni][2];
      const float z3 = a[3] + xv[bj] * wxr[ni][3];
      const float gg = tanh_fast(z0);
      const float ig = sigf(z1);
      const float fg = sigf(z2);
      const float og = sigf(z3);
      const float cc = gg * ig + cst[ni][bj] * fg;
      cnew[bj] = cc;
      const float hh = tanh_fast(cc) * og;
      // ldsH[batch_local][unit_local], stride 40 (80 B, 16B-aligned)
      ldsH[(wc * 64 + bj * 16 + l15) * 40 + (wr * 16 + ni * 4 + hi)] = (f16)hh;
    }
    __builtin_nontemporal_store(cnew, (f32x4*)(cme + ni * 4));
  }
  __syncthreads();

  // coalesced h-tile writeout: 128 rows x 32 units x 2B = 8 KB, 2 x 16B/thread
#pragma unroll
  for (int j = 0; j < 2; ++j) {
    const int q = tid + j * 256;
    const int row = q >> 2, uc = q & 3;
    const f16x8 v = *(const f16x8*)(ldsH + row * 40 + uc * 8);
    __builtin_nontemporal_store(v, (f16x8*)(hout + (size_t)(b0 + row) * 2048 + u0 + uc * 8));
  }
}

// y[b][o] = sum_k h[b][k]*Wy[o][k] + by[o]  (one-shot, fp32)
__global__ void out_proj(const f16* __restrict__ h, const float* __restrict__ Wy,
                         const float* __restrict__ by, float* __restrict__ y)
{
  const int gi = blockIdx.x * 256 + threadIdx.x;   // 65536
  const int o = gi & 127, b = gi >> 7;
  const f16* hr = h + (size_t)b * 2048;
  const float* wr = Wy + (size_t)o * 2048;
  float acc = 0.f;
  for (int k = 0; k < 2048; k += 8) {
    const f16x8 hv = *(const f16x8*)(hr + k);
    const float4 wa = *(const float4*)(wr + k);
    const float4 wb = *(const float4*)(wr + k + 4);
    acc += (float)hv[0] * wa.x + (float)hv[1] * wa.y + (float)hv[2] * wa.z + (float)hv[3] * wa.w
         + (float)hv[4] * wb.x + (float)hv[5] * wb.y + (float)hv[6] * wb.z + (float)hv[7] * wb.w;
  }
  y[gi] = acc + by[o];
}

extern "C" void kernel_launch(void* const* d_in, const int* in_sizes, int n_in,
                              void* d_out, int out_size, void* d_ws, size_t ws_size,
                              hipStream_t stream)
{
  const float* x  = (const float*)d_in[0];
  const float* Wg = (const float*)d_in[1];
  const float* bg = (const float*)d_in[2];
  const float* Wi = (const float*)d_in[3];
  const float* bi = (const float*)d_in[4];
  const float* Wf = (const float*)d_in[5];
  const float* bf = (const float*)d_in[6];
  const float* Wo = (const float*)d_in[7];
  const float* bo = (const float*)d_in[8];
  const float* Wy = (const float*)d_in[9];
  const float* by = (const float*)d_in[10];
  float* y = (float*)d_out;

  char* ws = (char*)d_ws;
  f16*   Wp = (f16*)(ws + OFF_WP);
  float* wx = (float*)(ws + OFF_WX);
  float* bb = (float*)(ws + OFF_BB);
  float* xT = (float*)(ws + OFF_XT);
  f16*   hA = (f16*)(ws + OFF_HA);
  f16*   hB = (f16*)(ws + OFF_HB);
  float* cb = (float*)(ws + OFF_CB);

  pack_weights<<<8192, 256, 0, stream>>>(Wg, Wi, Wf, Wo, bg, bi, bf, bo, Wp, wx, bb);
  transpose_x<<<2048, 256, 0, stream>>>(x, xT);
  zero_h<<<512, 256, 0, stream>>>(hA);

  (void)hipFuncSetAttribute((const void*)lstm_step,
                            hipFuncAttributeMaxDynamicSharedMemorySize, 131072);
  for (int t = 0; t < kS; ++t) {
    const f16* hin = (t & 1) ? hB : hA;
    f16*      hout = (t & 1) ? hA : hB;
    lstm_step<<<256, 256, 98304, stream>>>(Wp, wx, bb, xT, hin, hout, cb, t);
  }

  out_proj<<<256, 256, 0, stream>>>(hA, Wy, by, y);
}